// Round 1
// baseline (227.281 us; speedup 1.0000x reference)
//
#include <hip/hip_runtime.h>
#include <math.h>

typedef unsigned short u16;
typedef __attribute__((ext_vector_type(8))) short s16x8;
typedef __attribute__((ext_vector_type(4))) float f32x4;

#define NROWS 32768
#define DDIM 512
#define HALF 16384
#define TILE 128
#define KB 64
#define LDS_STRIDE 132   // elements; 264B rows: 8B-aligned for b64 writes, lane-group bank shift 16 -> 2-way (free)

__device__ __forceinline__ u16 f2bf(float f) {
  unsigned int u = __float_as_uint(f);
  unsigned int rounding = 0x7FFFu + ((u >> 16) & 1u);
  u += rounding;
  return (u16)(u >> 16);
}

__device__ __forceinline__ void block_atomic_sum(float v, float* dst) {
  #pragma unroll
  for (int o = 32; o > 0; o >>= 1) v += __shfl_down(v, o);
  __shared__ float red[4];
  int w = threadIdx.x >> 6;
  if ((threadIdx.x & 63) == 0) red[w] = v;
  __syncthreads();
  if (threadIdx.x == 0) {
    atomicAdd(dst, red[0] + red[1] + red[2] + red[3]);
  }
}

// Kernel 1: gather rows of combined=[z_a;z_b] via perm into bf16 z1/z2, fused with repr_loss partial sums.
// perm covers [0,N) exactly once, so summing (z_a[q]-z_b[q])^2 over gathered q == sum over all rows.
__global__ void gather_repr_kernel(const float* __restrict__ za, const float* __restrict__ zb,
                                   const int* __restrict__ perm, u16* __restrict__ z1,
                                   u16* __restrict__ z2, float* __restrict__ sums) {
  int idx = blockIdx.x * 256 + threadIdx.x;        // one thread per 8 elements
  int which = (idx >= HALF * (DDIM / 8)) ? 1 : 0;  // 0 -> z1, 1 -> z2
  int loc = which ? idx - HALF * (DDIM / 8) : idx;
  int r = loc >> 6;          // output row
  int c8 = (loc & 63) << 3;  // element offset of this 8-wide chunk
  int p = perm[(which ? HALF : 0) + r];
  int q = (p < NROWS) ? p : p - NROWS;
  const float4* pa = reinterpret_cast<const float4*>(za + (size_t)q * DDIM + c8);
  const float4* pb = reinterpret_cast<const float4*>(zb + (size_t)q * DDIM + c8);
  float4 a0 = pa[0], a1 = pa[1];
  float4 b0 = pb[0], b1 = pb[1];
  bool from_a = (p < NROWS);
  float4 g0 = from_a ? a0 : b0;
  float4 g1 = from_a ? a1 : b1;

  uint4 o;
  o.x = (unsigned)f2bf(g0.x) | ((unsigned)f2bf(g0.y) << 16);
  o.y = (unsigned)f2bf(g0.z) | ((unsigned)f2bf(g0.w) << 16);
  o.z = (unsigned)f2bf(g1.x) | ((unsigned)f2bf(g1.y) << 16);
  o.w = (unsigned)f2bf(g1.z) | ((unsigned)f2bf(g1.w) << 16);
  u16* dst = (which ? z2 : z1) + (size_t)r * DDIM + c8;
  *reinterpret_cast<uint4*>(dst) = o;

  float dx = a0.x - b0.x, dy = a0.y - b0.y, dz = a0.z - b0.z, dw = a0.w - b0.w;
  float ex = a1.x - b1.x, ey = a1.y - b1.y, ez = a1.z - b1.z, ew = a1.w - b1.w;
  float acc = dx * dx + dy * dy + dz * dz + dw * dw + ex * ex + ey * ey + ez * ez + ew * ew;
  block_atomic_sum(acc, &sums[0]);
}

// Kernel 2: gram partials. C = Z^T Z with Z [HALF][512] bf16. 128x128 tile per block,
// 4 waves each owning a 64x64 quadrant (4x4 frags of 16x16x32 MFMA). Split-K into nslice
// slices; each (mat,slice,tile) block writes raw fp32 partials (no atomics).
__global__ __launch_bounds__(256) void gram_kernel(const u16* __restrict__ z1,
                                                   const u16* __restrict__ z2,
                                                   float* __restrict__ parts,
                                                   int nslice, int ns_log2) {
  int b = blockIdx.x;
  int mat = b & 1;
  int rest = b >> 1;
  int slice = rest & (nslice - 1);
  int tile = rest >> ns_log2;
  int ti = (tile >> 2) * TILE;
  int tj = (tile & 3) * TILE;
  const u16* Z = mat ? z2 : z1;
  float* P = parts + ((size_t)(mat * nslice + slice)) * (DDIM * DDIM);

  __shared__ u16 ldsA[KB][LDS_STRIDE];
  __shared__ u16 ldsB[KB][LDS_STRIDE];

  int t = threadIdx.x;
  int lane = t & 63;
  int wave = t >> 6;
  int wrow = (wave >> 1) * 64;
  int wcol = (wave & 1) * 64;
  int g = lane >> 4;
  int c = lane & 15;

  f32x4 acc[4][4];
  #pragma unroll
  for (int m = 0; m < 4; ++m)
    #pragma unroll
    for (int n = 0; n < 4; ++n)
      #pragma unroll
      for (int r = 0; r < 4; ++r) acc[m][n][r] = 0.0f;

  int kspan = HALF >> ns_log2;
  int k0 = slice * kspan;
  for (int kk = k0; kk < k0 + kspan; kk += KB) {
    __syncthreads();
    // stage KB x 128 strips for column blocks ti and tj (row-major, padded stride)
    #pragma unroll
    for (int it = 0; it < 4; ++it) {
      int slot = t + it * 256;      // 0..1023
      int row = slot >> 4;          // 0..63
      int col8 = (slot & 15) << 3;  // 0..120
      uint4 va = *reinterpret_cast<const uint4*>(Z + (size_t)(kk + row) * DDIM + ti + col8);
      uint4 vb = *reinterpret_cast<const uint4*>(Z + (size_t)(kk + row) * DDIM + tj + col8);
      uint2* da = reinterpret_cast<uint2*>(&ldsA[row][col8]);
      da[0] = make_uint2(va.x, va.y);
      da[1] = make_uint2(va.z, va.w);
      uint2* db = reinterpret_cast<uint2*>(&ldsB[row][col8]);
      db[0] = make_uint2(vb.x, vb.y);
      db[1] = make_uint2(vb.z, vb.w);
    }
    __syncthreads();
    #pragma unroll
    for (int ks = 0; ks < KB; ks += 32) {
      s16x8 afr[4], bfr[4];
      #pragma unroll
      for (int m = 0; m < 4; ++m) {
        #pragma unroll
        for (int e = 0; e < 8; ++e) {
          afr[m][e] = (short)ldsA[ks + 8 * g + e][wrow + m * 16 + c];
          bfr[m][e] = (short)ldsB[ks + 8 * g + e][wcol + m * 16 + c];
        }
      }
      #pragma unroll
      for (int m = 0; m < 4; ++m)
        #pragma unroll
        for (int n = 0; n < 4; ++n)
          acc[m][n] = __builtin_amdgcn_mfma_f32_16x16x32_bf16(afr[m], bfr[n], acc[m][n], 0, 0, 0);
    }
  }
  // store raw partials; C/D layout: col = lane&15, row = 4*(lane>>4)+reg
  #pragma unroll
  for (int m = 0; m < 4; ++m)
    #pragma unroll
    for (int n = 0; n < 4; ++n)
      #pragma unroll
      for (int r = 0; r < 4; ++r) {
        int orow = ti + wrow + m * 16 + 4 * g + r;
        int ocol = tj + wcol + n * 16 + c;
        P[orow * DDIM + ocol] = acc[m][n][r];
      }
}

// Kernel 3: sum split-K partials, scale by 1/(half-1). cov = [cov1 | cov2] contiguous.
__global__ void reduce_parts_kernel(const float* __restrict__ parts, float* __restrict__ cov,
                                    int nslice) {
  int idx = blockIdx.x * 256 + threadIdx.x;  // float4 index over 2*512*512/4 = 131072
  int mat = idx >> 16;
  int off = idx & 65535;
  const float4* p = reinterpret_cast<const float4*>(parts) + (size_t)mat * nslice * 65536 + off;
  float sx = 0.f, sy = 0.f, sz = 0.f, sw = 0.f;
  for (int j = 0; j < nslice; ++j) {
    float4 v = p[(size_t)j * 65536];
    sx += v.x; sy += v.y; sz += v.z; sw += v.w;
  }
  const float inv = 1.0f / 16383.0f;
  float4 o; o.x = sx * inv; o.y = sy * inv; o.z = sz * inv; o.w = sw * inv;
  reinterpret_cast<float4*>(cov)[idx] = o;
}

// Kernel 4: E = (cov1 - I)(cov2 - I); accumulate frobenius sum of squares, E never stored.
__global__ void covdiff_kernel(const float* __restrict__ cov, float* __restrict__ sums) {
  const float* c1 = cov;
  const float* c2 = cov + DDIM * DDIM;
  int bx = blockIdx.x & 15, by = blockIdx.x >> 4;
  int col = bx * 32 + (threadIdx.x & 31);
  int ty = threadIdx.x >> 5;  // 0..7
  int r0 = by * 32;
  float e0 = 0.f, e1 = 0.f, e2 = 0.f, e3 = 0.f;
  for (int k = 0; k < DDIM; ++k) {
    float bv = c2[k * DDIM + col] - ((k == col) ? 1.0f : 0.0f);
    int row = r0 + ty;
    float a0 = c1[(row + 0) * DDIM + k] - ((row + 0 == k) ? 1.0f : 0.0f);
    float a1 = c1[(row + 8) * DDIM + k] - ((row + 8 == k) ? 1.0f : 0.0f);
    float a2 = c1[(row + 16) * DDIM + k] - ((row + 16 == k) ? 1.0f : 0.0f);
    float a3 = c1[(row + 24) * DDIM + k] - ((row + 24 == k) ? 1.0f : 0.0f);
    e0 = fmaf(a0, bv, e0);
    e1 = fmaf(a1, bv, e1);
    e2 = fmaf(a2, bv, e2);
    e3 = fmaf(a3, bv, e3);
  }
  float s = e0 * e0 + e1 * e1 + e2 * e2 + e3 * e3;
  block_atomic_sum(s, &sums[1]);
}

__global__ void finalize_kernel(const float* __restrict__ sums, float* __restrict__ out) {
  if (threadIdx.x == 0 && blockIdx.x == 0)
    out[0] = 25.0f * (sums[0] / 16777216.0f) + sqrtf(sums[1]);
}

extern "C" void kernel_launch(void* const* d_in, const int* in_sizes, int n_in,
                              void* d_out, int out_size, void* d_ws, size_t ws_size,
                              hipStream_t stream) {
  const float* za = (const float*)d_in[0];
  const float* zb = (const float*)d_in[1];
  const int* perm = (const int*)d_in[2];
  float* out = (float*)d_out;
  char* ws = (char*)d_ws;

  // pick split-K depth to fit workspace: need 256 + ns*2MB(parts) + 2MB(cov) + 32MB(z1,z2)
  int ns = 16, ns_log2 = 4;
  while (ns > 1) {
    size_t need = 256 + (size_t)2 * ns * DDIM * DDIM * 4 + (size_t)2 * DDIM * DDIM * 4 +
                  (size_t)2 * HALF * DDIM * 2;
    if (need <= ws_size) break;
    ns >>= 1;
    ns_log2--;
  }

  float* sums = (float*)ws;
  float* parts = (float*)(ws + 256);
  float* cov = (float*)(ws + 256 + (size_t)2 * ns * DDIM * DDIM * 4);
  u16* z1 = (u16*)(ws + 256 + (size_t)2 * ns * DDIM * DDIM * 4 + (size_t)2 * DDIM * DDIM * 4);
  u16* z2 = z1 + (size_t)HALF * DDIM;

  hipMemsetAsync(ws, 0, 256, stream);  // zero repr/frob accumulators
  gather_repr_kernel<<<2 * HALF * (DDIM / 8) / 256, 256, 0, stream>>>(za, zb, perm, z1, z2, sums);
  gram_kernel<<<2 * 16 * ns, 256, 0, stream>>>(z1, z2, parts, ns, ns_log2);
  reduce_parts_kernel<<<2 * DDIM * DDIM / 4 / 256, 256, 0, stream>>>(parts, cov, ns);
  covdiff_kernel<<<256, 256, 0, stream>>>(cov, sums);
  finalize_kernel<<<1, 64, 0, stream>>>(sums, out);
}

// Round 2
// 136.731 us; speedup vs baseline: 1.6622x; 1.6622x over previous
//
#include <hip/hip_runtime.h>
#include <math.h>

typedef unsigned short u16;
typedef __attribute__((ext_vector_type(8))) short s16x8;
typedef __attribute__((ext_vector_type(4))) float f32x4;

#define NROWS 32768
#define DDIM 512
#define HALF 16384
#define KB 64

__device__ __forceinline__ u16 f2bf(float f) {
  unsigned int u = __float_as_uint(f);
  unsigned int rounding = 0x7FFFu + ((u >> 16) & 1u);
  u += rounding;
  return (u16)(u >> 16);
}

__device__ __forceinline__ void block_atomic_sum(float v, float* dst) {
  #pragma unroll
  for (int o = 32; o > 0; o >>= 1) v += __shfl_down(v, o);
  __shared__ float red[4];
  int w = threadIdx.x >> 6;
  if ((threadIdx.x & 63) == 0) red[w] = v;
  __syncthreads();
  if (threadIdx.x == 0) atomicAdd(dst, red[0] + red[1] + red[2] + red[3]);
}

// Kernel 0: inverse permutation. inv[perm[i]] = i.
__global__ void inv_kernel(const int* __restrict__ perm, int* __restrict__ inv) {
  int i = blockIdx.x * 256 + threadIdx.x;
  inv[perm[i]] = i;
}

// Kernel 1: sequential read of z_a/z_b (full MLP), fused repr partial, bf16 convert,
// scattered row write into z1/z2 by rank inv[row]. All perm values < NROWS, so every
// gathered row comes from z_a; z_b only feeds repr_loss. Gram is row-order invariant,
// so rank placement is valid.
__global__ __launch_bounds__(256) void scatter_repr_kernel(
    const float* __restrict__ za, const float* __restrict__ zb, const int* __restrict__ inv,
    u16* __restrict__ z1, u16* __restrict__ z2, float* __restrict__ sums) {
  int t = threadIdx.x;
  float4 A[4][2], B[4][2];
  int rk[4];
  #pragma unroll
  for (int i = 0; i < 4; ++i) {
    int chunk = (i * 2048 + blockIdx.x) * 256 + t;
    int row = chunk >> 6;
    int c8 = (chunk & 63) << 3;
    const float4* pa = reinterpret_cast<const float4*>(za + (size_t)row * DDIM + c8);
    const float4* pb = reinterpret_cast<const float4*>(zb + (size_t)row * DDIM + c8);
    A[i][0] = pa[0]; A[i][1] = pa[1];
    B[i][0] = pb[0]; B[i][1] = pb[1];
    rk[i] = inv[row];
  }
  float acc = 0.0f;
  #pragma unroll
  for (int i = 0; i < 4; ++i) {
    float4 a0 = A[i][0], a1 = A[i][1], b0 = B[i][0], b1 = B[i][1];
    float dx = a0.x - b0.x, dy = a0.y - b0.y, dz = a0.z - b0.z, dw = a0.w - b0.w;
    float ex = a1.x - b1.x, ey = a1.y - b1.y, ez = a1.z - b1.z, ew = a1.w - b1.w;
    acc += dx*dx + dy*dy + dz*dz + dw*dw + ex*ex + ey*ey + ez*ez + ew*ew;
    uint4 o;
    o.x = (unsigned)f2bf(a0.x) | ((unsigned)f2bf(a0.y) << 16);
    o.y = (unsigned)f2bf(a0.z) | ((unsigned)f2bf(a0.w) << 16);
    o.z = (unsigned)f2bf(a1.x) | ((unsigned)f2bf(a1.y) << 16);
    o.w = (unsigned)f2bf(a1.z) | ((unsigned)f2bf(a1.w) << 16);
    int chunk = (i * 2048 + blockIdx.x) * 256 + t;
    int c8 = (chunk & 63) << 3;
    int r = rk[i];
    u16* dst = (r < HALF) ? (z1 + (size_t)r * DDIM + c8) : (z2 + (size_t)(r - HALF) * DDIM + c8);
    *reinterpret_cast<uint4*>(dst) = o;
  }
  block_atomic_sum(acc, &sums[0]);
}

// XOR swizzle: element (k, col) of a KBx128 tile lives at u16 index col*64 + (k ^ sw(col)).
// sw multiple of 8 keeps 8-aligned k-runs contiguous and b128-aligned.
__device__ __forceinline__ int swz(int col) { return (((col >> 3) + col) & 7) << 3; }

__device__ __forceinline__ void store8(u16* lds, int c0, int kp, uint4 v0, uint4 v1) {
  const ushort* h0 = reinterpret_cast<const ushort*>(&v0);
  const ushort* h1 = reinterpret_cast<const ushort*>(&v1);
  #pragma unroll
  for (int j = 0; j < 8; ++j) {
    int col = c0 + j;
    unsigned w = (unsigned)h0[j] | ((unsigned)h1[j] << 16);
    *reinterpret_cast<unsigned*>(lds + col * KB + ((kp ^ swz(col)))) = w;
  }
}

// Kernel 2: gram partials, upper-triangular 128x128 tiles only (gram is symmetric).
// LDS is [col][k] transposed+swizzled so fragments are single ds_read_b128 loads.
__global__ __launch_bounds__(256) void gram_kernel(const u16* __restrict__ z1,
                                                   const u16* __restrict__ z2,
                                                   float* __restrict__ parts,
                                                   int nslice, int ns_log2) {
  int b = blockIdx.x;
  int mat = b & 1;
  int rest = b >> 1;
  int slice = rest & (nslice - 1);
  int tile = rest >> ns_log2;  // 0..9 upper-tri
  int bi, bj;
  if (tile < 4)      { bi = 0; bj = tile; }
  else if (tile < 7) { bi = 1; bj = tile - 3; }
  else if (tile < 9) { bi = 2; bj = tile - 5; }
  else               { bi = 3; bj = 3; }
  int ti = bi * 128, tj = bj * 128;
  const u16* Z = mat ? z2 : z1;
  float* P = parts + ((size_t)(mat * nslice + slice)) * (DDIM * DDIM);

  __shared__ u16 ldsA[128 * KB];
  __shared__ u16 ldsB[128 * KB];
  const u16* ldsBp = (ti == tj) ? ldsA : ldsB;

  int t = threadIdx.x;
  int lane = t & 63;
  int wave = t >> 6;
  int wrow = (wave >> 1) * 64;
  int wcol = (wave & 1) * 64;
  int g = lane >> 4;
  int c = lane & 15;
  int h = lane >> 4;
  int c0 = (lane & 15) << 3;

  f32x4 acc[4][4];
  #pragma unroll
  for (int m = 0; m < 4; ++m)
    #pragma unroll
    for (int n = 0; n < 4; ++n)
      #pragma unroll
      for (int r = 0; r < 4; ++r) acc[m][n][r] = 0.0f;

  int kspan = HALF >> ns_log2;
  int k0 = slice * kspan;
  for (int kk = k0; kk < k0 + kspan; kk += KB) {
    __syncthreads();
    #pragma unroll
    for (int it = 0; it < 2; ++it) {
      int kp = 8 * wave + 32 * it + 2 * h;  // even row in [0,64)
      const u16* src0 = Z + (size_t)(kk + kp) * DDIM;
      const u16* src1 = src0 + DDIM;
      uint4 va0 = *reinterpret_cast<const uint4*>(src0 + ti + c0);
      uint4 va1 = *reinterpret_cast<const uint4*>(src1 + ti + c0);
      store8(ldsA, c0, kp, va0, va1);
      if (ti != tj) {
        uint4 vb0 = *reinterpret_cast<const uint4*>(src0 + tj + c0);
        uint4 vb1 = *reinterpret_cast<const uint4*>(src1 + tj + c0);
        store8(ldsB, c0, kp, vb0, vb1);
      }
    }
    __syncthreads();
    #pragma unroll
    for (int ks = 0; ks < KB; ks += 32) {
      s16x8 afr[4], bfr[4];
      #pragma unroll
      for (int m = 0; m < 4; ++m) {
        int colA = wrow + m * 16 + c;
        afr[m] = *reinterpret_cast<const s16x8*>(ldsA + colA * KB + ((ks + 8 * g) ^ swz(colA)));
        int colB = wcol + m * 16 + c;
        bfr[m] = *reinterpret_cast<const s16x8*>(ldsBp + colB * KB + ((ks + 8 * g) ^ swz(colB)));
      }
      #pragma unroll
      for (int m = 0; m < 4; ++m)
        #pragma unroll
        for (int n = 0; n < 4; ++n)
          acc[m][n] = __builtin_amdgcn_mfma_f32_16x16x32_bf16(afr[m], bfr[n], acc[m][n], 0, 0, 0);
    }
  }
  // C/D layout: col = lane&15, row = 4*(lane>>4)+reg (verified by round-1 pass)
  #pragma unroll
  for (int m = 0; m < 4; ++m)
    #pragma unroll
    for (int n = 0; n < 4; ++n)
      #pragma unroll
      for (int r = 0; r < 4; ++r) {
        int orow = ti + wrow + m * 16 + 4 * g + r;
        int ocol = tj + wcol + n * 16 + c;
        P[orow * DDIM + ocol] = acc[m][n][r];
      }
}

// Kernel 3: sum split-K partials over the written triangle, scale by 1/(half-1),
// write full symmetric cov (transposed scalar stores for the lower off-diag blocks).
__global__ void reduce_parts_kernel(const float* __restrict__ parts, float* __restrict__ cov,
                                    int nslice) {
  int idx = blockIdx.x * 256 + threadIdx.x;  // 0..81919
  int mat = (idx >= 40960) ? 1 : 0;
  int tl = idx - mat * 40960;
  int region = tl >> 12;  // 0..9
  int o = tl & 4095;
  int bi, bj;
  if (region < 4)      { bi = 0; bj = region; }
  else if (region < 7) { bi = 1; bj = region - 3; }
  else if (region < 9) { bi = 2; bj = region - 5; }
  else                 { bi = 3; bj = 3; }
  int r = bi * 128 + (o >> 5);
  int cc = bj * 128 + ((o & 31) << 2);
  const float* base = parts + (size_t)mat * nslice * (DDIM * DDIM);
  float sx = 0.f, sy = 0.f, sz = 0.f, sw = 0.f;
  for (int j = 0; j < nslice; ++j) {
    float4 v = *reinterpret_cast<const float4*>(base + (size_t)j * (DDIM * DDIM) + r * DDIM + cc);
    sx += v.x; sy += v.y; sz += v.z; sw += v.w;
  }
  const float inv = 1.0f / 16383.0f;
  sx *= inv; sy *= inv; sz *= inv; sw *= inv;
  float* cv = cov + (size_t)mat * (DDIM * DDIM);
  float4 ov; ov.x = sx; ov.y = sy; ov.z = sz; ov.w = sw;
  *reinterpret_cast<float4*>(cv + r * DDIM + cc) = ov;
  if (bi != bj) {
    cv[(cc + 0) * DDIM + r] = sx;
    cv[(cc + 1) * DDIM + r] = sy;
    cv[(cc + 2) * DDIM + r] = sz;
    cv[(cc + 3) * DDIM + r] = sw;
  }
}

// Kernel 4: E = (cov1 - I)(cov2 - I); frobenius sum of squares, E never stored.
__global__ void covdiff_kernel(const float* __restrict__ cov, float* __restrict__ sums) {
  const float* c1 = cov;
  const float* c2 = cov + DDIM * DDIM;
  int bx = blockIdx.x & 15, by = blockIdx.x >> 4;
  int col = bx * 32 + (threadIdx.x & 31);
  int ty = threadIdx.x >> 5;  // 0..7
  int r0 = by * 32;
  float e0 = 0.f, e1 = 0.f, e2 = 0.f, e3 = 0.f;
  for (int k = 0; k < DDIM; ++k) {
    float bv = c2[k * DDIM + col] - ((k == col) ? 1.0f : 0.0f);
    int row = r0 + ty;
    float a0 = c1[(row + 0) * DDIM + k] - ((row + 0 == k) ? 1.0f : 0.0f);
    float a1 = c1[(row + 8) * DDIM + k] - ((row + 8 == k) ? 1.0f : 0.0f);
    float a2 = c1[(row + 16) * DDIM + k] - ((row + 16 == k) ? 1.0f : 0.0f);
    float a3 = c1[(row + 24) * DDIM + k] - ((row + 24 == k) ? 1.0f : 0.0f);
    e0 = fmaf(a0, bv, e0);
    e1 = fmaf(a1, bv, e1);
    e2 = fmaf(a2, bv, e2);
    e3 = fmaf(a3, bv, e3);
  }
  float s = e0 * e0 + e1 * e1 + e2 * e2 + e3 * e3;
  block_atomic_sum(s, &sums[1]);
}

__global__ void finalize_kernel(const float* __restrict__ sums, float* __restrict__ out) {
  if (threadIdx.x == 0 && blockIdx.x == 0)
    out[0] = 25.0f * (sums[0] / 16777216.0f) + sqrtf(sums[1]);
}

extern "C" void kernel_launch(void* const* d_in, const int* in_sizes, int n_in,
                              void* d_out, int out_size, void* d_ws, size_t ws_size,
                              hipStream_t stream) {
  const float* za = (const float*)d_in[0];
  const float* zb = (const float*)d_in[1];
  const int* perm = (const int*)d_in[2];
  float* out = (float*)d_out;
  char* ws = (char*)d_ws;

  // workspace: sums(256) | parts(2*ns*1MB) | cov(2MB) | z1,z2(32MB) | inv(128KB)
  int ns = 32, ns_log2 = 5;
  while (ns > 1) {
    size_t need = 256 + (size_t)2 * ns * DDIM * DDIM * 4 + (size_t)2 * DDIM * DDIM * 4 +
                  (size_t)2 * HALF * DDIM * 2 + (size_t)NROWS * 4;
    if (need <= ws_size) break;
    ns >>= 1;
    ns_log2--;
  }

  float* sums = (float*)ws;
  float* parts = (float*)(ws + 256);
  size_t off = 256 + (size_t)2 * ns * DDIM * DDIM * 4;
  float* cov = (float*)(ws + off);
  off += (size_t)2 * DDIM * DDIM * 4;
  u16* z1 = (u16*)(ws + off);
  u16* z2 = z1 + (size_t)HALF * DDIM;
  off += (size_t)2 * HALF * DDIM * 2;
  int* inv = (int*)(ws + off);

  hipMemsetAsync(ws, 0, 256, stream);
  inv_kernel<<<NROWS / 256, 256, 0, stream>>>(perm, inv);
  scatter_repr_kernel<<<2048, 256, 0, stream>>>(za, zb, inv, z1, z2, sums);
  gram_kernel<<<2 * 10 * ns, 256, 0, stream>>>(z1, z2, parts, ns, ns_log2);
  reduce_parts_kernel<<<320, 256, 0, stream>>>(parts, cov, ns);
  covdiff_kernel<<<256, 256, 0, stream>>>(cov, sums);
  finalize_kernel<<<1, 64, 0, stream>>>(sums, out);
}

// Round 3
// 105.739 us; speedup vs baseline: 2.1494x; 1.2931x over previous
//
#include <hip/hip_runtime.h>
#include <math.h>

typedef unsigned short u16;
typedef __attribute__((ext_vector_type(8))) short s16x8;
typedef __attribute__((ext_vector_type(4))) float f32x4;

#define NROWS 32768
#define DDIM 512
#define HALF 16384
#define KB 64
#define CSLICE 4

__device__ __forceinline__ u16 f2bf(float f) {
  unsigned int u = __float_as_uint(f);
  unsigned int rounding = 0x7FFFu + ((u >> 16) & 1u);
  u += rounding;
  return (u16)(u >> 16);
}

__device__ __forceinline__ void block_atomic_sum(float v, float* dst) {
  #pragma unroll
  for (int o = 32; o > 0; o >>= 1) v += __shfl_down(v, o);
  __shared__ float red[4];
  int w = threadIdx.x >> 6;
  if ((threadIdx.x & 63) == 0) red[w] = v;
  __syncthreads();
  if (threadIdx.x == 0) atomicAdd(dst, red[0] + red[1] + red[2] + red[3]);
}

// Kernel 0: inverse permutation. inv[perm[i]] = i.
__global__ void inv_kernel(const int* __restrict__ perm, int* __restrict__ inv) {
  int i = blockIdx.x * 256 + threadIdx.x;
  inv[perm[i]] = i;
}

__device__ __forceinline__ float chunk_proc(float4 a0, float4 a1, float4 b0, float4 b1,
                                            int r, int c8, u16* z1, u16* z2) {
  uint4 o;
  o.x = (unsigned)f2bf(a0.x) | ((unsigned)f2bf(a0.y) << 16);
  o.y = (unsigned)f2bf(a0.z) | ((unsigned)f2bf(a0.w) << 16);
  o.z = (unsigned)f2bf(a1.x) | ((unsigned)f2bf(a1.y) << 16);
  o.w = (unsigned)f2bf(a1.z) | ((unsigned)f2bf(a1.w) << 16);
  u16* dst = (r < HALF) ? (z1 + (size_t)r * DDIM + c8) : (z2 + (size_t)(r - HALF) * DDIM + c8);
  *reinterpret_cast<uint4*>(dst) = o;
  float dx = a0.x - b0.x, dy = a0.y - b0.y, dz = a0.z - b0.z, dw = a0.w - b0.w;
  float ex = a1.x - b1.x, ey = a1.y - b1.y, ez = a1.z - b1.z, ew = a1.w - b1.w;
  return dx*dx + dy*dy + dz*dz + dw*dw + ex*ex + ey*ey + ez*ez + ew*ew;
}

// Kernel 1: sequential read of z_a/z_b, fused repr partial, bf16 convert, scattered row
// write into z1/z2 by rank inv[row]. All 20 loads issued before any use (sched_barrier
// fence) to keep memory-level parallelism — round-2 showed the compiler sank them.
__global__ __launch_bounds__(256) void scatter_repr_kernel(
    const float* __restrict__ za, const float* __restrict__ zb, const int* __restrict__ inv,
    u16* __restrict__ z1, u16* __restrict__ z2, float* __restrict__ sums) {
  int t = threadIdx.x;
  int ch0 = (0 * 2048 + blockIdx.x) * 256 + t;
  int ch1 = (1 * 2048 + blockIdx.x) * 256 + t;
  int ch2 = (2 * 2048 + blockIdx.x) * 256 + t;
  int ch3 = (3 * 2048 + blockIdx.x) * 256 + t;
  int row0 = ch0 >> 6, row1 = ch1 >> 6, row2 = ch2 >> 6, row3 = ch3 >> 6;
  int c80 = (ch0 & 63) << 3, c81 = (ch1 & 63) << 3, c82 = (ch2 & 63) << 3, c83 = (ch3 & 63) << 3;
  const float4* pa0 = reinterpret_cast<const float4*>(za + (size_t)row0 * DDIM + c80);
  const float4* pa1 = reinterpret_cast<const float4*>(za + (size_t)row1 * DDIM + c81);
  const float4* pa2 = reinterpret_cast<const float4*>(za + (size_t)row2 * DDIM + c82);
  const float4* pa3 = reinterpret_cast<const float4*>(za + (size_t)row3 * DDIM + c83);
  const float4* pb0 = reinterpret_cast<const float4*>(zb + (size_t)row0 * DDIM + c80);
  const float4* pb1 = reinterpret_cast<const float4*>(zb + (size_t)row1 * DDIM + c81);
  const float4* pb2 = reinterpret_cast<const float4*>(zb + (size_t)row2 * DDIM + c82);
  const float4* pb3 = reinterpret_cast<const float4*>(zb + (size_t)row3 * DDIM + c83);
  float4 a00 = pa0[0], a01 = pa0[1];
  float4 a10 = pa1[0], a11 = pa1[1];
  float4 a20 = pa2[0], a21 = pa2[1];
  float4 a30 = pa3[0], a31 = pa3[1];
  float4 b00 = pb0[0], b01 = pb0[1];
  float4 b10 = pb1[0], b11 = pb1[1];
  float4 b20 = pb2[0], b21 = pb2[1];
  float4 b30 = pb3[0], b31 = pb3[1];
  int r0 = inv[row0], r1 = inv[row1], r2 = inv[row2], r3 = inv[row3];
  __builtin_amdgcn_sched_barrier(0);
  float acc = 0.0f;
  acc += chunk_proc(a00, a01, b00, b01, r0, c80, z1, z2);
  acc += chunk_proc(a10, a11, b10, b11, r1, c81, z1, z2);
  acc += chunk_proc(a20, a21, b20, b21, r2, c82, z1, z2);
  acc += chunk_proc(a30, a31, b30, b31, r3, c83, z1, z2);
  block_atomic_sum(acc, &sums[0]);
}

// XOR swizzle: element (k, col) of a KBx128 tile lives at u16 index col*64 + (k ^ sw(col)).
__device__ __forceinline__ int swz(int col) { return (((col >> 3) + col) & 7) << 3; }

__device__ __forceinline__ void store8(u16* lds, int c0, int kp, uint4 v0, uint4 v1) {
  const ushort* h0 = reinterpret_cast<const ushort*>(&v0);
  const ushort* h1 = reinterpret_cast<const ushort*>(&v1);
  #pragma unroll
  for (int j = 0; j < 8; ++j) {
    int col = c0 + j;
    unsigned w = (unsigned)h0[j] | ((unsigned)h1[j] << 16);
    *reinterpret_cast<unsigned*>(lds + col * KB + ((kp ^ swz(col)))) = w;
  }
}

// Kernel 2: gram partials, upper-triangular 128x128 tiles only (gram is symmetric).
// LDS is [col][k] transposed+swizzled so fragments are single ds_read_b128 loads.
__global__ __launch_bounds__(256) void gram_kernel(const u16* __restrict__ z1,
                                                   const u16* __restrict__ z2,
                                                   float* __restrict__ parts,
                                                   int nslice, int ns_log2) {
  int b = blockIdx.x;
  int mat = b & 1;
  int rest = b >> 1;
  int slice = rest & (nslice - 1);
  int tile = rest >> ns_log2;  // 0..9 upper-tri
  int bi, bj;
  if (tile < 4)      { bi = 0; bj = tile; }
  else if (tile < 7) { bi = 1; bj = tile - 3; }
  else if (tile < 9) { bi = 2; bj = tile - 5; }
  else               { bi = 3; bj = 3; }
  int ti = bi * 128, tj = bj * 128;
  const u16* Z = mat ? z2 : z1;
  float* P = parts + ((size_t)(mat * nslice + slice)) * (DDIM * DDIM);

  __shared__ u16 ldsA[128 * KB];
  __shared__ u16 ldsB[128 * KB];
  const u16* ldsBp = (ti == tj) ? ldsA : ldsB;

  int t = threadIdx.x;
  int lane = t & 63;
  int wave = t >> 6;
  int wrow = (wave >> 1) * 64;
  int wcol = (wave & 1) * 64;
  int g = lane >> 4;
  int c = lane & 15;
  int h = lane >> 4;
  int c0 = (lane & 15) << 3;

  f32x4 acc[4][4];
  #pragma unroll
  for (int m = 0; m < 4; ++m)
    #pragma unroll
    for (int n = 0; n < 4; ++n)
      #pragma unroll
      for (int r = 0; r < 4; ++r) acc[m][n][r] = 0.0f;

  int kspan = HALF >> ns_log2;
  int k0 = slice * kspan;
  for (int kk = k0; kk < k0 + kspan; kk += KB) {
    __syncthreads();
    #pragma unroll
    for (int it = 0; it < 2; ++it) {
      int kp = 8 * wave + 32 * it + 2 * h;  // even row in [0,64)
      const u16* src0 = Z + (size_t)(kk + kp) * DDIM;
      const u16* src1 = src0 + DDIM;
      uint4 va0 = *reinterpret_cast<const uint4*>(src0 + ti + c0);
      uint4 va1 = *reinterpret_cast<const uint4*>(src1 + ti + c0);
      store8(ldsA, c0, kp, va0, va1);
      if (ti != tj) {
        uint4 vb0 = *reinterpret_cast<const uint4*>(src0 + tj + c0);
        uint4 vb1 = *reinterpret_cast<const uint4*>(src1 + tj + c0);
        store8(ldsB, c0, kp, vb0, vb1);
      }
    }
    __syncthreads();
    #pragma unroll
    for (int ks = 0; ks < KB; ks += 32) {
      s16x8 afr[4], bfr[4];
      #pragma unroll
      for (int m = 0; m < 4; ++m) {
        int colA = wrow + m * 16 + c;
        afr[m] = *reinterpret_cast<const s16x8*>(ldsA + colA * KB + ((ks + 8 * g) ^ swz(colA)));
        int colB = wcol + m * 16 + c;
        bfr[m] = *reinterpret_cast<const s16x8*>(ldsBp + colB * KB + ((ks + 8 * g) ^ swz(colB)));
      }
      #pragma unroll
      for (int m = 0; m < 4; ++m)
        #pragma unroll
        for (int n = 0; n < 4; ++n)
          acc[m][n] = __builtin_amdgcn_mfma_f32_16x16x32_bf16(afr[m], bfr[n], acc[m][n], 0, 0, 0);
    }
  }
  #pragma unroll
  for (int m = 0; m < 4; ++m)
    #pragma unroll
    for (int n = 0; n < 4; ++n)
      #pragma unroll
      for (int r = 0; r < 4; ++r) {
        int orow = ti + wrow + m * 16 + 4 * g + r;
        int ocol = tj + wcol + n * 16 + c;
        P[orow * DDIM + ocol] = acc[m][n][r];
      }
}

// Kernel 3: sum split-K partials over the triangle, scale by 1/(half-1), write full
// symmetric cov (transposed scalar stores for the lower off-diag blocks).
__global__ void reduce_parts_kernel(const float* __restrict__ parts, float* __restrict__ cov,
                                    int nslice) {
  int idx = blockIdx.x * 256 + threadIdx.x;  // 0..81919
  int mat = (idx >= 40960) ? 1 : 0;
  int tl = idx - mat * 40960;
  int region = tl >> 12;  // 0..9
  int o = tl & 4095;
  int bi, bj;
  if (region < 4)      { bi = 0; bj = region; }
  else if (region < 7) { bi = 1; bj = region - 3; }
  else if (region < 9) { bi = 2; bj = region - 5; }
  else                 { bi = 3; bj = 3; }
  int r = bi * 128 + (o >> 5);
  int cc = bj * 128 + ((o & 31) << 2);
  const float* base = parts + (size_t)mat * nslice * (DDIM * DDIM);
  float sx = 0.f, sy = 0.f, sz = 0.f, sw = 0.f;
  for (int j = 0; j < nslice; ++j) {
    float4 v = *reinterpret_cast<const float4*>(base + (size_t)j * (DDIM * DDIM) + r * DDIM + cc);
    sx += v.x; sy += v.y; sz += v.z; sw += v.w;
  }
  const float inv = 1.0f / 16383.0f;
  sx *= inv; sy *= inv; sz *= inv; sw *= inv;
  float* cv = cov + (size_t)mat * (DDIM * DDIM);
  float4 ov; ov.x = sx; ov.y = sy; ov.z = sz; ov.w = sw;
  *reinterpret_cast<float4*>(cv + r * DDIM + cc) = ov;
  if (bi != bj) {
    cv[(cc + 0) * DDIM + r] = sx;
    cv[(cc + 1) * DDIM + r] = sy;
    cv[(cc + 2) * DDIM + r] = sz;
    cv[(cc + 3) * DDIM + r] = sw;
  }
}

// Kernel 4a: partial E tiles. grid = 16x16 tiles x CSLICE k-slices, LDS-staged panels,
// I-subtraction folded into staging. Partials to pcov (reused z1 region).
__global__ __launch_bounds__(256) void covdiff_part_kernel(const float* __restrict__ cov,
                                                           float* __restrict__ pcov) {
  int bid = blockIdx.x;
  int bx = bid & 15, by = (bid >> 4) & 15, sl = bid >> 8;
  int r0 = by * 32, c0 = bx * 32, ks = sl * 128;
  const float* c1 = cov;
  const float* c2 = cov + DDIM * DDIM;
  __shared__ float ldsA[32 * 132];
  __shared__ float ldsB[128 * 33];
  int t = threadIdx.x;
  #pragma unroll
  for (int j = 0; j < 4; ++j) {
    int f4 = t + 256 * j;   // 0..1023
    int row = f4 >> 5;      // 0..31
    int k4 = (f4 & 31) << 2;
    float4 v = *reinterpret_cast<const float4*>(c1 + (size_t)(r0 + row) * DDIM + ks + k4);
    int gr = r0 + row;
    if (gr == ks + k4 + 0) v.x -= 1.f;
    if (gr == ks + k4 + 1) v.y -= 1.f;
    if (gr == ks + k4 + 2) v.z -= 1.f;
    if (gr == ks + k4 + 3) v.w -= 1.f;
    *reinterpret_cast<float4*>(&ldsA[row * 132 + k4]) = v;
  }
  {
    int c = t & 31;
    int kb = t >> 5;  // 0..7
    #pragma unroll
    for (int j = 0; j < 16; ++j) {
      int k = kb + 8 * j;
      float v = c2[(size_t)(ks + k) * DDIM + c0 + c];
      if (ks + k == c0 + c) v -= 1.f;
      ldsB[k * 33 + c] = v;
    }
  }
  __syncthreads();
  int col = t & 31;
  int ty = t >> 5;  // 0..7 -> rows ty*4 + 0..3
  float e0 = 0.f, e1 = 0.f, e2 = 0.f, e3 = 0.f;
  #pragma unroll 4
  for (int k = 0; k < 128; ++k) {
    float bv = ldsB[k * 33 + col];
    e0 = fmaf(ldsA[(ty * 4 + 0) * 132 + k], bv, e0);
    e1 = fmaf(ldsA[(ty * 4 + 1) * 132 + k], bv, e1);
    e2 = fmaf(ldsA[(ty * 4 + 2) * 132 + k], bv, e2);
    e3 = fmaf(ldsA[(ty * 4 + 3) * 132 + k], bv, e3);
  }
  float* P = pcov + (size_t)sl * (DDIM * DDIM);
  P[(r0 + ty * 4 + 0) * DDIM + c0 + col] = e0;
  P[(r0 + ty * 4 + 1) * DDIM + c0 + col] = e1;
  P[(r0 + ty * 4 + 2) * DDIM + c0 + col] = e2;
  P[(r0 + ty * 4 + 3) * DDIM + c0 + col] = e3;
}

// Kernel 4b: sum slices, square, reduce to sums[1].
__global__ void covred_kernel(const float* __restrict__ pcov, float* __restrict__ sums) {
  int idx = blockIdx.x * 256 + threadIdx.x;  // 0..65535 float4 slots
  float sx = 0.f, sy = 0.f, sz = 0.f, sw = 0.f;
  #pragma unroll
  for (int j = 0; j < CSLICE; ++j) {
    float4 v = reinterpret_cast<const float4*>(pcov)[idx + j * 65536];
    sx += v.x; sy += v.y; sz += v.z; sw += v.w;
  }
  float q = sx * sx + sy * sy + sz * sz + sw * sw;
  block_atomic_sum(q, &sums[1]);
}

__global__ void finalize_kernel(const float* __restrict__ sums, float* __restrict__ out) {
  if (threadIdx.x == 0 && blockIdx.x == 0)
    out[0] = 25.0f * (sums[0] / 16777216.0f) + sqrtf(sums[1]);
}

extern "C" void kernel_launch(void* const* d_in, const int* in_sizes, int n_in,
                              void* d_out, int out_size, void* d_ws, size_t ws_size,
                              hipStream_t stream) {
  const float* za = (const float*)d_in[0];
  const float* zb = (const float*)d_in[1];
  const int* perm = (const int*)d_in[2];
  float* out = (float*)d_out;
  char* ws = (char*)d_ws;

  // workspace: sums(256) | parts(2*ns*1MB) | cov(2MB) | z1,z2(32MB) | inv(128KB)
  int ns = 32, ns_log2 = 5;
  while (ns > 1) {
    size_t need = 256 + (size_t)2 * ns * DDIM * DDIM * 4 + (size_t)2 * DDIM * DDIM * 4 +
                  (size_t)2 * HALF * DDIM * 2 + (size_t)NROWS * 4;
    if (need <= ws_size) break;
    ns >>= 1;
    ns_log2--;
  }

  float* sums = (float*)ws;
  float* parts = (float*)(ws + 256);
  size_t off = 256 + (size_t)2 * ns * DDIM * DDIM * 4;
  float* cov = (float*)(ws + off);
  off += (size_t)2 * DDIM * DDIM * 4;
  u16* z1 = (u16*)(ws + off);
  u16* z2 = z1 + (size_t)HALF * DDIM;
  float* pcov = (float*)z1;  // reused after gram consumes z1/z2 (CSLICE*1MB <= 16MB)
  off += (size_t)2 * HALF * DDIM * 2;
  int* inv = (int*)(ws + off);

  hipMemsetAsync(ws, 0, 256, stream);
  inv_kernel<<<NROWS / 256, 256, 0, stream>>>(perm, inv);
  scatter_repr_kernel<<<2048, 256, 0, stream>>>(za, zb, inv, z1, z2, sums);
  gram_kernel<<<2 * 10 * ns, 256, 0, stream>>>(z1, z2, parts, ns, ns_log2);
  reduce_parts_kernel<<<320, 256, 0, stream>>>(parts, cov, ns);
  covdiff_part_kernel<<<16 * 16 * CSLICE, 256, 0, stream>>>(cov, pcov);
  covred_kernel<<<256, 256, 0, stream>>>(pcov, sums);
  finalize_kernel<<<1, 64, 0, stream>>>(sums, out);
}

// Round 5
// 94.410 us; speedup vs baseline: 2.4074x; 1.1200x over previous
//
#include <hip/hip_runtime.h>
#include <math.h>

typedef unsigned short u16;
typedef __attribute__((ext_vector_type(8))) short s16x8;
typedef __attribute__((ext_vector_type(4))) float f32x4;

#define NROWS 32768
#define DDIM 512
#define HALF 16384
#define KB 64
#define CSLICE 4
#define NSLICE 32
#define NSLOG2 5

__device__ __forceinline__ u16 f2bf(float f) {
  unsigned int u = __float_as_uint(f);
  unsigned int rounding = 0x7FFFu + ((u >> 16) & 1u);
  u += rounding;
  return (u16)(u >> 16);
}

__device__ __forceinline__ float bf2f(u16 h) {
  return __uint_as_float(((unsigned)h) << 16);
}

__device__ __forceinline__ void block_atomic_sum(float v, float* dst) {
  #pragma unroll
  for (int o = 32; o > 0; o >>= 1) v += __shfl_down(v, o);
  __shared__ float red[4];
  int w = threadIdx.x >> 6;
  if ((threadIdx.x & 63) == 0) red[w] = v;
  __syncthreads();
  if (threadIdx.x == 0) atomicAdd(dst, red[0] + red[1] + red[2] + red[3]);
}

// Kernel 0: inverse permutation. inv[perm[i]] = i.
__global__ void inv_kernel(const int* __restrict__ perm, int* __restrict__ inv) {
  int i = blockIdx.x * 256 + threadIdx.x;
  inv[perm[i]] = i;
}

__device__ __forceinline__ float chunk_proc(float4 a0, float4 a1, float4 b0, float4 b1,
                                            int r, int c8, u16* z1, u16* z2) {
  uint4 o;
  o.x = (unsigned)f2bf(a0.x) | ((unsigned)f2bf(a0.y) << 16);
  o.y = (unsigned)f2bf(a0.z) | ((unsigned)f2bf(a0.w) << 16);
  o.z = (unsigned)f2bf(a1.x) | ((unsigned)f2bf(a1.y) << 16);
  o.w = (unsigned)f2bf(a1.z) | ((unsigned)f2bf(a1.w) << 16);
  u16* dst = (r < HALF) ? (z1 + (size_t)r * DDIM + c8) : (z2 + (size_t)(r - HALF) * DDIM + c8);
  *reinterpret_cast<uint4*>(dst) = o;
  float dx = a0.x - b0.x, dy = a0.y - b0.y, dz = a0.z - b0.z, dw = a0.w - b0.w;
  float ex = a1.x - b1.x, ey = a1.y - b1.y, ez = a1.z - b1.z, ew = a1.w - b1.w;
  return dx*dx + dy*dy + dz*dz + dw*dw + ex*ex + ey*ey + ez*ez + ew*ew;
}

// Kernel 1: sequential read of z_a/z_b, fused repr partial, bf16 convert, scattered row
// write into z1/z2 by rank inv[row]. Input-only scalar asm wall: reading one component of
// each loaded float4 forces all 20 loads issued+completed before any compute can start
// (loads cannot sink past an asm consuming their result). Tied "+v" on float4 doesn't
// compile (round 4); input "v" on scalars does the same job.
__global__ __launch_bounds__(256) void scatter_repr_kernel(
    const float* __restrict__ za, const float* __restrict__ zb, const int* __restrict__ inv,
    u16* __restrict__ z1, u16* __restrict__ z2, float* __restrict__ sums) {
  int t = threadIdx.x;
  int ch0 = (0 * 2048 + blockIdx.x) * 256 + t;
  int ch1 = (1 * 2048 + blockIdx.x) * 256 + t;
  int ch2 = (2 * 2048 + blockIdx.x) * 256 + t;
  int ch3 = (3 * 2048 + blockIdx.x) * 256 + t;
  int row0 = ch0 >> 6, row1 = ch1 >> 6, row2 = ch2 >> 6, row3 = ch3 >> 6;
  int c80 = (ch0 & 63) << 3, c81 = (ch1 & 63) << 3, c82 = (ch2 & 63) << 3, c83 = (ch3 & 63) << 3;
  const float4* pa0 = reinterpret_cast<const float4*>(za + (size_t)row0 * DDIM + c80);
  const float4* pa1 = reinterpret_cast<const float4*>(za + (size_t)row1 * DDIM + c81);
  const float4* pa2 = reinterpret_cast<const float4*>(za + (size_t)row2 * DDIM + c82);
  const float4* pa3 = reinterpret_cast<const float4*>(za + (size_t)row3 * DDIM + c83);
  const float4* pb0 = reinterpret_cast<const float4*>(zb + (size_t)row0 * DDIM + c80);
  const float4* pb1 = reinterpret_cast<const float4*>(zb + (size_t)row1 * DDIM + c81);
  const float4* pb2 = reinterpret_cast<const float4*>(zb + (size_t)row2 * DDIM + c82);
  const float4* pb3 = reinterpret_cast<const float4*>(zb + (size_t)row3 * DDIM + c83);
  float4 a00 = pa0[0], a01 = pa0[1];
  float4 a10 = pa1[0], a11 = pa1[1];
  float4 a20 = pa2[0], a21 = pa2[1];
  float4 a30 = pa3[0], a31 = pa3[1];
  float4 b00 = pb0[0], b01 = pb0[1];
  float4 b10 = pb1[0], b11 = pb1[1];
  float4 b20 = pb2[0], b21 = pb2[1];
  float4 b30 = pb3[0], b31 = pb3[1];
  int r0 = inv[row0], r1 = inv[row1], r2 = inv[row2], r3 = inv[row3];
  asm volatile("" :: "v"(a00.x), "v"(a01.x), "v"(a10.x), "v"(a11.x),
                     "v"(a20.x), "v"(a21.x), "v"(a30.x), "v"(a31.x),
                     "v"(b00.x), "v"(b01.x), "v"(b10.x), "v"(b11.x),
                     "v"(b20.x), "v"(b21.x), "v"(b30.x), "v"(b31.x),
                     "v"(r0), "v"(r1), "v"(r2), "v"(r3));
  float acc = 0.0f;
  acc += chunk_proc(a00, a01, b00, b01, r0, c80, z1, z2);
  acc += chunk_proc(a10, a11, b10, b11, r1, c81, z1, z2);
  acc += chunk_proc(a20, a21, b20, b21, r2, c82, z1, z2);
  acc += chunk_proc(a30, a31, b30, b31, r3, c83, z1, z2);
  block_atomic_sum(acc, &sums[0]);
}

// XOR swizzle: element (k, col) of a KBx128 tile lives at u16 index col*64 + (k ^ sw(col)).
__device__ __forceinline__ int swz(int col) { return (((col >> 3) + col) & 7) << 3; }

__device__ __forceinline__ void store8(u16* lds, int c0, int kp, uint4 v0, uint4 v1) {
  const ushort* h0 = reinterpret_cast<const ushort*>(&v0);
  const ushort* h1 = reinterpret_cast<const ushort*>(&v1);
  #pragma unroll
  for (int j = 0; j < 8; ++j) {
    int col = c0 + j;
    unsigned w = (unsigned)h0[j] | ((unsigned)h1[j] << 16);
    *reinterpret_cast<unsigned*>(lds + col * KB + ((kp ^ swz(col)))) = w;
  }
}

// Kernel 2: gram partials (bf16), upper-triangular 128x128 tiles, reg-staged 2-phase
// double buffer: next K-tile's global loads issue before the MFMA cluster so HBM
// latency hides under compute. LDS is [col][k] transposed+swizzled (b128 frag reads).
__global__ __launch_bounds__(256) void gram_kernel(const u16* __restrict__ z1,
                                                   const u16* __restrict__ z2,
                                                   u16* __restrict__ parts) {
  int b = blockIdx.x;
  int mat = b & 1;
  int rest = b >> 1;
  int slice = rest & (NSLICE - 1);
  int tile = rest >> NSLOG2;  // 0..9 upper-tri
  int bi, bj;
  if (tile < 4)      { bi = 0; bj = tile; }
  else if (tile < 7) { bi = 1; bj = tile - 3; }
  else if (tile < 9) { bi = 2; bj = tile - 5; }
  else               { bi = 3; bj = 3; }
  int ti = bi * 128, tj = bj * 128;
  const u16* Z = mat ? z2 : z1;
  bool dual = (ti != tj);
  u16* P = parts + ((size_t)(mat * NSLICE + slice)) * (DDIM * DDIM);

  __shared__ u16 ldsA[128 * KB];
  __shared__ u16 ldsB[128 * KB];
  const u16* ldsBp = dual ? ldsB : ldsA;

  int t = threadIdx.x;
  int lane = t & 63;
  int wave = t >> 6;
  int wrow = (wave >> 1) * 64;
  int wcol = (wave & 1) * 64;
  int g = lane >> 4;
  int c = lane & 15;
  int h = lane >> 4;
  int c0 = (lane & 15) << 3;
  int kp0 = 8 * wave + 2 * h;  // even row in [0,32)

  f32x4 acc[4][4];
  #pragma unroll
  for (int m = 0; m < 4; ++m)
    #pragma unroll
    for (int n = 0; n < 4; ++n)
      #pragma unroll
      for (int r = 0; r < 4; ++r) acc[m][n][r] = 0.0f;

  uint4 xa0, xa1, xa2, xa3, xb0, xb1, xb2, xb3;
  uint4 ya0, ya1, ya2, ya3, yb0, yb1, yb2, yb3;

#define GLOAD(p, kkv) { \
    const u16* s0 = Z + (size_t)((kkv) + kp0) * DDIM; \
    const u16* s1 = Z + (size_t)((kkv) + kp0 + 32) * DDIM; \
    p##a0 = *reinterpret_cast<const uint4*>(s0 + ti + c0); \
    p##a1 = *reinterpret_cast<const uint4*>(s0 + DDIM + ti + c0); \
    p##a2 = *reinterpret_cast<const uint4*>(s1 + ti + c0); \
    p##a3 = *reinterpret_cast<const uint4*>(s1 + DDIM + ti + c0); \
    if (dual) { \
      p##b0 = *reinterpret_cast<const uint4*>(s0 + tj + c0); \
      p##b1 = *reinterpret_cast<const uint4*>(s0 + DDIM + tj + c0); \
      p##b2 = *reinterpret_cast<const uint4*>(s1 + tj + c0); \
      p##b3 = *reinterpret_cast<const uint4*>(s1 + DDIM + tj + c0); \
    } }

#define GSTORE(p) { \
    store8(ldsA, c0, kp0, p##a0, p##a1); \
    store8(ldsA, c0, kp0 + 32, p##a2, p##a3); \
    if (dual) { \
      store8(ldsB, c0, kp0, p##b0, p##b1); \
      store8(ldsB, c0, kp0 + 32, p##b2, p##b3); \
    } }

#define COMPUTE() { \
    _Pragma("unroll") \
    for (int ks = 0; ks < KB; ks += 32) { \
      s16x8 afr[4], bfr[4]; \
      _Pragma("unroll") \
      for (int m = 0; m < 4; ++m) { \
        int colA = wrow + m * 16 + c; \
        afr[m] = *reinterpret_cast<const s16x8*>(ldsA + colA * KB + ((ks + 8 * g) ^ swz(colA))); \
        int colB = wcol + m * 16 + c; \
        bfr[m] = *reinterpret_cast<const s16x8*>(ldsBp + colB * KB + ((ks + 8 * g) ^ swz(colB))); \
      } \
      _Pragma("unroll") \
      for (int m = 0; m < 4; ++m) \
        _Pragma("unroll") \
        for (int n = 0; n < 4; ++n) \
          acc[m][n] = __builtin_amdgcn_mfma_f32_16x16x32_bf16(afr[m], bfr[n], acc[m][n], 0, 0, 0); \
    } }

  const int kspan = HALF >> NSLOG2;  // 512
  const int k0 = slice * kspan;
  GLOAD(x, k0);
  for (int kk = k0; kk < k0 + kspan; kk += 2 * KB) {
    __syncthreads();
    GSTORE(x);
    __syncthreads();
    GLOAD(y, kk + KB);   // tiles-per-slice is even, always in range
    COMPUTE();
    __syncthreads();
    GSTORE(y);
    __syncthreads();
    if (kk + 2 * KB < k0 + kspan) GLOAD(x, kk + 2 * KB);
    COMPUTE();
  }
#undef GLOAD
#undef GSTORE
#undef COMPUTE

  #pragma unroll
  for (int m = 0; m < 4; ++m)
    #pragma unroll
    for (int n = 0; n < 4; ++n)
      #pragma unroll
      for (int r = 0; r < 4; ++r) {
        int orow = ti + wrow + m * 16 + 4 * g + r;
        int ocol = tj + wcol + n * 16 + c;
        P[orow * DDIM + ocol] = f2bf(acc[m][n][r]);
      }
}

// Kernel 3: sum bf16 split-K partials over the triangle, scale by 1/(half-1), write full
// symmetric f32 cov (transposed scalar stores for the lower off-diag blocks).
__global__ void reduce_parts_kernel(const u16* __restrict__ parts, float* __restrict__ cov) {
  int idx = blockIdx.x * 256 + threadIdx.x;  // 0..81919
  int mat = (idx >= 40960) ? 1 : 0;
  int tl = idx - mat * 40960;
  int region = tl >> 12;  // 0..9
  int o = tl & 4095;
  int bi, bj;
  if (region < 4)      { bi = 0; bj = region; }
  else if (region < 7) { bi = 1; bj = region - 3; }
  else if (region < 9) { bi = 2; bj = region - 5; }
  else                 { bi = 3; bj = 3; }
  int r = bi * 128 + (o >> 5);
  int cc = bj * 128 + ((o & 31) << 2);
  const u16* base = parts + (size_t)mat * NSLICE * (DDIM * DDIM);
  float sx = 0.f, sy = 0.f, sz = 0.f, sw = 0.f;
  #pragma unroll 4
  for (int j = 0; j < NSLICE; ++j) {
    ushort4 v = *reinterpret_cast<const ushort4*>(base + (size_t)j * (DDIM * DDIM) + r * DDIM + cc);
    sx += bf2f(v.x); sy += bf2f(v.y); sz += bf2f(v.z); sw += bf2f(v.w);
  }
  const float inv = 1.0f / 16383.0f;
  sx *= inv; sy *= inv; sz *= inv; sw *= inv;
  float* cv = cov + (size_t)mat * (DDIM * DDIM);
  float4 ov; ov.x = sx; ov.y = sy; ov.z = sz; ov.w = sw;
  *reinterpret_cast<float4*>(cv + r * DDIM + cc) = ov;
  if (bi != bj) {
    cv[(cc + 0) * DDIM + r] = sx;
    cv[(cc + 1) * DDIM + r] = sy;
    cv[(cc + 2) * DDIM + r] = sz;
    cv[(cc + 3) * DDIM + r] = sw;
  }
}

// Kernel 4a: partial E tiles. grid = 16x16 tiles x CSLICE k-slices, LDS-staged panels,
// I-subtraction folded into staging. Partials to pcov (reused z1 region).
__global__ __launch_bounds__(256) void covdiff_part_kernel(const float* __restrict__ cov,
                                                           float* __restrict__ pcov) {
  int bid = blockIdx.x;
  int bx = bid & 15, by = (bid >> 4) & 15, sl = bid >> 8;
  int r0 = by * 32, c0 = bx * 32, ks = sl * 128;
  const float* c1 = cov;
  const float* c2 = cov + DDIM * DDIM;
  __shared__ float ldsA[32 * 132];
  __shared__ float ldsB[128 * 33];
  int t = threadIdx.x;
  #pragma unroll
  for (int j = 0; j < 4; ++j) {
    int f4 = t + 256 * j;   // 0..1023
    int row = f4 >> 5;      // 0..31
    int k4 = (f4 & 31) << 2;
    float4 v = *reinterpret_cast<const float4*>(c1 + (size_t)(r0 + row) * DDIM + ks + k4);
    int gr = r0 + row;
    if (gr == ks + k4 + 0) v.x -= 1.f;
    if (gr == ks + k4 + 1) v.y -= 1.f;
    if (gr == ks + k4 + 2) v.z -= 1.f;
    if (gr == ks + k4 + 3) v.w -= 1.f;
    *reinterpret_cast<float4*>(&ldsA[row * 132 + k4]) = v;
  }
  {
    int c = t & 31;
    int kb = t >> 5;  // 0..7
    #pragma unroll
    for (int j = 0; j < 16; ++j) {
      int k = kb + 8 * j;
      float v = c2[(size_t)(ks + k) * DDIM + c0 + c];
      if (ks + k == c0 + c) v -= 1.f;
      ldsB[k * 33 + c] = v;
    }
  }
  __syncthreads();
  int col = t & 31;
  int ty = t >> 5;  // 0..7 -> rows ty*4 + 0..3
  float e0 = 0.f, e1 = 0.f, e2 = 0.f, e3 = 0.f;
  #pragma unroll 4
  for (int k = 0; k < 128; ++k) {
    float bv = ldsB[k * 33 + col];
    e0 = fmaf(ldsA[(ty * 4 + 0) * 132 + k], bv, e0);
    e1 = fmaf(ldsA[(ty * 4 + 1) * 132 + k], bv, e1);
    e2 = fmaf(ldsA[(ty * 4 + 2) * 132 + k], bv, e2);
    e3 = fmaf(ldsA[(ty * 4 + 3) * 132 + k], bv, e3);
  }
  float* P = pcov + (size_t)sl * (DDIM * DDIM);
  P[(r0 + ty * 4 + 0) * DDIM + c0 + col] = e0;
  P[(r0 + ty * 4 + 1) * DDIM + c0 + col] = e1;
  P[(r0 + ty * 4 + 2) * DDIM + c0 + col] = e2;
  P[(r0 + ty * 4 + 3) * DDIM + c0 + col] = e3;
}

// Kernel 4b: sum slices, square, reduce to sums[1].
__global__ void covred_kernel(const float* __restrict__ pcov, float* __restrict__ sums) {
  int idx = blockIdx.x * 256 + threadIdx.x;  // 0..65535 float4 slots
  float sx = 0.f, sy = 0.f, sz = 0.f, sw = 0.f;
  #pragma unroll
  for (int j = 0; j < CSLICE; ++j) {
    float4 v = reinterpret_cast<const float4*>(pcov)[idx + j * 65536];
    sx += v.x; sy += v.y; sz += v.z; sw += v.w;
  }
  float q = sx * sx + sy * sy + sz * sz + sw * sw;
  block_atomic_sum(q, &sums[1]);
}

__global__ void finalize_kernel(const float* __restrict__ sums, float* __restrict__ out) {
  if (threadIdx.x == 0 && blockIdx.x == 0)
    out[0] = 25.0f * (sums[0] / 16777216.0f) + sqrtf(sums[1]);
}

extern "C" void kernel_launch(void* const* d_in, const int* in_sizes, int n_in,
                              void* d_out, int out_size, void* d_ws, size_t ws_size,
                              hipStream_t stream) {
  const float* za = (const float*)d_in[0];
  const float* zb = (const float*)d_in[1];
  const int* perm = (const int*)d_in[2];
  float* out = (float*)d_out;
  char* ws = (char*)d_ws;

  // workspace: sums(256) | parts bf16 (2*NSLICE*0.5MB = 32MB) | cov(2MB) | z1,z2(32MB) | inv(128KB)
  float* sums = (float*)ws;
  u16* parts = (u16*)(ws + 256);
  size_t off = 256 + (size_t)2 * NSLICE * DDIM * DDIM * 2;
  float* cov = (float*)(ws + off);
  off += (size_t)2 * DDIM * DDIM * 4;
  u16* z1 = (u16*)(ws + off);
  u16* z2 = z1 + (size_t)HALF * DDIM;
  float* pcov = (float*)z1;  // reused after gram consumes z1/z2 (CSLICE*1MB <= 16MB)
  off += (size_t)2 * HALF * DDIM * 2;
  int* inv = (int*)(ws + off);

  (void)hipMemsetAsync(ws, 0, 256, stream);
  inv_kernel<<<NROWS / 256, 256, 0, stream>>>(perm, inv);
  scatter_repr_kernel<<<2048, 256, 0, stream>>>(za, zb, inv, z1, z2, sums);
  gram_kernel<<<2 * 10 * NSLICE, 256, 0, stream>>>(z1, z2, parts);
  reduce_parts_kernel<<<320, 256, 0, stream>>>(parts, cov);
  covdiff_part_kernel<<<16 * 16 * CSLICE, 256, 0, stream>>>(cov, pcov);
  covred_kernel<<<256, 256, 0, stream>>>(pcov, sums);
  finalize_kernel<<<1, 64, 0, stream>>>(sums, out);
}